// Round 9
// baseline (301.352 us; speedup 1.0000x reference)
//
#include <hip/hip_runtime.h>

#define HID 64
#define BSHIFT 9            // 512 nodes per bucket
#define NPB 512
#define P3TILE 4096         // edges per block-tile in partition
#define HISTB 512           // hist blocks in fused hist+input kernel
#define PREPB 96            // prep_w blocks fused into hist_input
#define NT 12               // nodes per tile (per wave): 8334 waves ~= capacity

typedef unsigned int uint;
typedef unsigned short ushort;
typedef unsigned char uchar;
typedef float f32x2 __attribute__((ext_vector_type(2)));
typedef float f32x4 __attribute__((ext_vector_type(4)));
typedef short bf16x8 __attribute__((ext_vector_type(8)));

__device__ inline ushort f2b(float f) {  // fp32 -> bf16 RNE
    uint u = __float_as_uint(f);
    return (ushort)((u + 0x7fffu + ((u >> 16) & 1u)) >> 16);
}

__device__ inline float b2f(ushort b) { return __uint_as_float((uint)b << 16); }

// unpack 16 fp8-e4m3 (uint4) and accumulate into a[8] float2 pairs.
__device__ inline void accf8(f32x2* a, uint4 hv) {
    a[0] += __builtin_bit_cast(f32x2, __builtin_amdgcn_cvt_pk_f32_fp8(hv.x, false));
    a[1] += __builtin_bit_cast(f32x2, __builtin_amdgcn_cvt_pk_f32_fp8(hv.x, true));
    a[2] += __builtin_bit_cast(f32x2, __builtin_amdgcn_cvt_pk_f32_fp8(hv.y, false));
    a[3] += __builtin_bit_cast(f32x2, __builtin_amdgcn_cvt_pk_f32_fp8(hv.y, true));
    a[4] += __builtin_bit_cast(f32x2, __builtin_amdgcn_cvt_pk_f32_fp8(hv.z, false));
    a[5] += __builtin_bit_cast(f32x2, __builtin_amdgcn_cvt_pk_f32_fp8(hv.z, true));
    a[6] += __builtin_bit_cast(f32x2, __builtin_amdgcn_cvt_pk_f32_fp8(hv.w, false));
    a[7] += __builtin_bit_cast(f32x2, __builtin_amdgcn_cvt_pk_f32_fp8(hv.w, true));
}

__device__ inline uchar f2fp8(float f) {
    return (uchar)(__builtin_amdgcn_cvt_pk_fp8_f32(f, f, 0, false) & 0xff);
}

// ------- fused: bucket histogram + input transform + weight prep -------

__global__ __launch_bounds__(256) void hist_input(const int* __restrict__ dst,
                                                  int* __restrict__ bcnt, int e, int nb,
                                                  const float* __restrict__ x,
                                                  const float* __restrict__ W_in,
                                                  const float* __restrict__ b_in,
                                                  ushort* __restrict__ hb,
                                                  uchar* __restrict__ h8, int n,
                                                  int inb,
                                                  const float* __restrict__ Ws,
                                                  const float* __restrict__ Wn,
                                                  ushort* __restrict__ Wcat) {
    __shared__ float smem[576];
    int t = threadIdx.x;
    int b = blockIdx.x;
    if (b < HISTB) {
        int* lh = (int*)smem;
        lh[t] = 0;
        __syncthreads();
        for (int i = b * 256 + t; i < e; i += HISTB * 256)
            atomicAdd(&lh[dst[i] >> BSHIFT], 1);
        __syncthreads();
        if (t < nb && lh[t]) atomicAdd(&bcnt[t], lh[t]);
        return;
    }
    if (b >= HISTB + inb) {   // weight prep range
        int i = (b - HISTB - inb) * 256 + t;
        if (i < 3 * 8192) {
            int l = i >> 13;
            int r = i & 8191;
            int j = r >> 7;
            int k = r & 127;
            float v = (k < 64) ? Ws[l * 4096 + j * 64 + k]
                               : Wn[l * 4096 + j * 64 + (k - 64)];
            Wcat[i] = f2b(v);
        }
        return;
    }
    int ib = b - HISTB;
    float* WlT = smem;          // [8][64]
    float* bl = smem + 512;     // [64]
    for (int i = t; i < 512; i += 256) {
        int j = i >> 3, k = i & 7;
        WlT[k * 64 + j] = W_in[i];
    }
    if (t < 64) bl[t] = b_in[t];
    __syncthreads();
    int total2 = n * 32;
    for (int i = ib * 256 + t; i < total2; i += inb * 256) {
        int v = i >> 5;
        int jp = i & 31;
        int j0 = jp * 2, j1 = jp * 2 + 1;
        const float* xr = x + (size_t)v * 8;
        float s0 = bl[j0], s1 = bl[j1];
#pragma unroll
        for (int k = 0; k < 8; ++k) {
            float xv = xr[k];
            s0 += xv * WlT[k * 64 + j0];
            s1 += xv * WlT[k * 64 + j1];
        }
        float o0 = fmaxf(s0, 0.0f), o1 = fmaxf(s1, 0.0f);
        ((uint*)hb)[i] = (uint)f2b(o0) | ((uint)f2b(o1) << 16);
        int pk = __builtin_amdgcn_cvt_pk_fp8_f32(o0, o1, 0, false);
        *(ushort*)&h8[(size_t)2 * i] = (ushort)(pk & 0xffff);
    }
}

__global__ void bucket_scan(const int* __restrict__ bcnt, int* __restrict__ bbase,
                            int* __restrict__ bcur, int* __restrict__ offsets,
                            int e, int nb, int n) {
    __shared__ int sd[256];
    int t = threadIdx.x;
    int v = (t < nb) ? bcnt[t] : 0;
    sd[t] = v;
    __syncthreads();
    for (int off = 1; off < 256; off <<= 1) {
        int u = (t >= off) ? sd[t - off] : 0;
        __syncthreads();
        sd[t] += u;
        __syncthreads();
    }
    int excl = t ? sd[t - 1] : 0;
    if (t < nb) { bbase[t] = excl; bcur[t] = excl; }
    if (t == nb) bbase[t] = e;
    if (t == 0) offsets[n] = e;
}

// partition edges into bucket-contiguous packed (src<<9 | dst&511) array.
__global__ __launch_bounds__(256) void partition(const int* __restrict__ src,
                                                 const int* __restrict__ dst,
                                                 int* __restrict__ bcur,
                                                 int* __restrict__ pair, int e, int nb) {
    __shared__ int lh[256], cb[256];
    int t = threadIdx.x;
    int base = blockIdx.x * P3TILE;
    lh[t] = 0;
    __syncthreads();
    int s[16], d[16], r[16];
    if (base + P3TILE <= e) {
        const int4* s4 = (const int4*)(src + base);
        const int4* d4 = (const int4*)(dst + base);
#pragma unroll
        for (int k = 0; k < 4; ++k) {
            int4 sv = s4[t * 4 + k];
            int4 dv = d4[t * 4 + k];
            s[k * 4 + 0] = sv.x; s[k * 4 + 1] = sv.y;
            s[k * 4 + 2] = sv.z; s[k * 4 + 3] = sv.w;
            d[k * 4 + 0] = dv.x; d[k * 4 + 1] = dv.y;
            d[k * 4 + 2] = dv.z; d[k * 4 + 3] = dv.w;
        }
#pragma unroll
        for (int k = 0; k < 16; ++k)
            r[k] = atomicAdd(&lh[d[k] >> BSHIFT], 1);
        __syncthreads();
        if (t < nb && lh[t]) cb[t] = atomicAdd(&bcur[t], lh[t]);
        __syncthreads();
#pragma unroll
        for (int k = 0; k < 16; ++k)
            pair[cb[d[k] >> BSHIFT] + r[k]] = (s[k] << BSHIFT) | (d[k] & (NPB - 1));
    } else {
#pragma unroll
        for (int k = 0; k < 16; ++k) {
            int i = base + t * 16 + k;
            if (i < e) {
                s[k] = src[i];
                d[k] = dst[i];
                r[k] = atomicAdd(&lh[d[k] >> BSHIFT], 1);
            }
        }
        __syncthreads();
        if (t < nb && lh[t]) cb[t] = atomicAdd(&bcur[t], lh[t]);
        __syncthreads();
#pragma unroll
        for (int k = 0; k < 16; ++k) {
            int i = base + t * 16 + k;
            if (i < e)
                pair[cb[d[k] >> BSHIFT] + r[k]] = (s[k] << BSHIFT) | (d[k] & (NPB - 1));
        }
    }
}

// 1024 threads/block: 16 waves for latency hiding
__global__ __launch_bounds__(1024) void build_csr(const int* __restrict__ pair,
                                                  const int* __restrict__ bbase,
                                                  int* __restrict__ offsets,
                                                  float* __restrict__ invdeg,
                                                  int* __restrict__ col, int n) {
    __shared__ int bins[NPB], cur[NPB], sd[NPB];
    int b = blockIdx.x, t = threadIdx.x;
    int cbase = bbase[b], cend = bbase[b + 1];
    int v0 = b << BSHIFT;
    if (t < NPB) bins[t] = 0;
    __syncthreads();
    for (int i = cbase + t; i < cend; i += 1024)
        atomicAdd(&bins[pair[i] & (NPB - 1)], 1);
    __syncthreads();
    int d = (t < NPB) ? bins[t] : 0;
    if (t < NPB) sd[t] = d;
    __syncthreads();
    for (int off = 1; off < NPB; off <<= 1) {
        int u = (t < NPB && t >= off) ? sd[t - off] : 0;
        __syncthreads();
        if (t < NPB) sd[t] += u;
        __syncthreads();
    }
    if (t < NPB) {
        int excl = sd[t] - d;
        cur[t] = excl;
        int v = v0 + t;
        if (v < n) {
            offsets[v] = cbase + excl;
            invdeg[v] = d > 0 ? 1.0f / (float)d : 0.0f;
        }
    }
    __syncthreads();
    for (int i = cbase + t; i < cend; i += 1024) {
        int p = pair[i];
        int pos = atomicAdd(&cur[p & (NPB - 1)], 1);
        col[cbase + pos] = p >> BSHIFT;
    }
}

// -------- fused aggregate + transform: one wave owns a 12-node tile --------
// 12-node tiles -> 8334 waves (2084 blocks x 4), matching the 2048-block /
// 8192-wave CU capacity (vs 6252 waves at 16-node tiles = 24% under-fill).
// The gather is latency-bound, so service rate tracks resident wave count.
// MFMA stays 16x16 with 4 dead rows (MFMA is <1% utilized - free). No new
// barriers (r7 lesson). hb tile staged once in wave-private LDS (r8 win).
// h8 is double-buffered (hin != hout) to avoid cross-tile races.

template <int LAST>
__global__ __launch_bounds__(256) void agg_tf(
    const uchar* __restrict__ h8in, const ushort* __restrict__ hbm,
    ushort* __restrict__ hbout, uchar* __restrict__ h8out,
    float* __restrict__ outF,
    const int* __restrict__ offsets, const int* __restrict__ col,
    const float* __restrict__ invdeg,
    const ushort* __restrict__ Wcat, const float* __restrict__ bias,
    const float* __restrict__ gamma, const float* __restrict__ beta, int n) {
    __shared__ ushort nmlds[4][NT][72];   // neighbor means, pad 72
    __shared__ ushort hbs[4][NT][76];     // staged hb tile, pad 76
    int t = threadIdx.x, lane = t & 63, wid = t >> 6;
    int ntiles = (n + NT - 1) / NT;
    int tile = blockIdx.x * 4 + wid;
    if (tile >= ntiles) return;
    int m0 = tile * NT;
    // ---- stage this wave's hb tile (NT rows x 64 cols bf16) ----
    {
        int row = lane >> 2;
        int ch = lane & 3;
        if (row < NT) {
            int node = m0 + row;
            int nl = node < n ? node : n - 1;
            const ushort* srcp = hbm + (size_t)nl * HID;
            *(uint4*)&hbs[wid][row][ch * 8] = *(const uint4*)&srcp[ch * 8];
            *(uint4*)&hbs[wid][row][32 + ch * 8] = *(const uint4*)&srcp[32 + ch * 8];
        }
    }
    int q = lane >> 4;          // quarter -> node within pass
    int fl = lane & 15;         // col staging lane
    int e4 = lane & 3;          // which 16B of the 64B row
    int sl = (lane >> 2) & 3;   // edge slot
    // ---- aggregate NT nodes in NT/4 passes of 4 ----
    for (int p = 0; p < NT / 4; ++p) {
        int v = m0 + p * 4 + q;
        int vv = v < n ? v : n - 1;
        int o0 = offsets[vv], o1 = offsets[vv + 1];
        int deg = o1 - o0;
        const int* cp = col + o0;
        int deg16 = deg & ~15;
        f32x2 acc2[8];
        float* af = (float*)acc2;
#pragma unroll
        for (int k = 0; k < 8; ++k) acc2[k] = f32x2{0.f, 0.f};
        for (int base = 0; base < deg16; base += 16) {
            int idx16 = cp[base + fl];
#pragma unroll
            for (int jj = 0; jj < 16; jj += 4) {
                int ne = __shfl(idx16, q * 16 + jj + sl);
                uint4 hv = *(const uint4*)&h8in[(size_t)ne * HID + e4 * 16];
                accf8(acc2, hv);
            }
        }
        for (int jj = 0; jj < 16; jj += 4) {
            if (deg16 + jj >= deg) break;   // uniform within quarter
            int j = deg16 + jj + sl;
            if (j < deg) {
                int ne = cp[j];
                uint4 hv = *(const uint4*)&h8in[(size_t)ne * HID + e4 * 16];
                accf8(acc2, hv);
            }
        }
#pragma unroll
        for (int k = 0; k < 16; ++k) {
            af[k] += __shfl_xor(af[k], 4);
            af[k] += __shfl_xor(af[k], 8);
        }
        if (sl == 0) {
            float s = invdeg[vv];
            uint4 lo, hi;
            lo.x = (uint)f2b(af[0] * s) | ((uint)f2b(af[1] * s) << 16);
            lo.y = (uint)f2b(af[2] * s) | ((uint)f2b(af[3] * s) << 16);
            lo.z = (uint)f2b(af[4] * s) | ((uint)f2b(af[5] * s) << 16);
            lo.w = (uint)f2b(af[6] * s) | ((uint)f2b(af[7] * s) << 16);
            hi.x = (uint)f2b(af[8] * s) | ((uint)f2b(af[9] * s) << 16);
            hi.y = (uint)f2b(af[10] * s) | ((uint)f2b(af[11] * s) << 16);
            hi.z = (uint)f2b(af[12] * s) | ((uint)f2b(af[13] * s) << 16);
            hi.w = (uint)f2b(af[14] * s) | ((uint)f2b(af[15] * s) << 16);
            int row = p * 4 + q;
            *(uint4*)&nmlds[wid][row][e4 * 16] = lo;
            *(uint4*)&nmlds[wid][row][e4 * 16 + 8] = hi;
        }
    }
    // LDS slabs are wave-private: no barrier needed (lgkmcnt ordering only).
    // ---- transform (round-3 math; A-frags + residual from LDS) ----
    int c = lane & 15, g = lane >> 4;
    int cr = c < NT ? c : NT - 1;       // clamp LDS row (rows >= NT unwritten)
    bf16x8 Bf[4][4];
#pragma unroll
    for (int tt = 0; tt < 4; ++tt)
#pragma unroll
        for (int s = 0; s < 4; ++s)
            Bf[s][tt] = *(const bf16x8*)&Wcat[(tt * 16 + c) * 128 + s * 32 + g * 8];
    float bcol[4], gcol[4], btc[4];
#pragma unroll
    for (int tt = 0; tt < 4; ++tt) {
        bcol[tt] = bias[tt * 16 + c];
        gcol[tt] = gamma[tt * 16 + c];
        btc[tt] = beta[tt * 16 + c];
    }
    bf16x8 Af[4];
#pragma unroll
    for (int s = 0; s < 2; ++s)
        Af[s] = *(const bf16x8*)&hbs[wid][cr][s * 32 + g * 8];
#pragma unroll
    for (int s = 0; s < 2; ++s)
        Af[2 + s] = *(const bf16x8*)&nmlds[wid][cr][s * 32 + g * 8];
    f32x4 acc[4] = {{0, 0, 0, 0}, {0, 0, 0, 0}, {0, 0, 0, 0}, {0, 0, 0, 0}};
#pragma unroll
    for (int tt = 0; tt < 4; ++tt)
#pragma unroll
        for (int s = 0; s < 4; ++s)
            acc[tt] = __builtin_amdgcn_mfma_f32_16x16x32_bf16(Af[s], Bf[s][tt],
                                                             acc[tt], 0, 0, 0);
    float v[4][4];
#pragma unroll
    for (int tt = 0; tt < 4; ++tt)
#pragma unroll
        for (int r = 0; r < 4; ++r) v[tt][r] = acc[tt][r] + bcol[tt];
#pragma unroll
    for (int r = 0; r < 4; ++r) {
        float s = v[0][r] + v[1][r] + v[2][r] + v[3][r];
        s += __shfl_xor(s, 1);
        s += __shfl_xor(s, 2);
        s += __shfl_xor(s, 4);
        s += __shfl_xor(s, 8);
        float mu = s * (1.0f / 64.0f);
        float ss = 0.f;
#pragma unroll
        for (int tt = 0; tt < 4; ++tt) {
            float d = v[tt][r] - mu;
            ss += d * d;
        }
        ss += __shfl_xor(ss, 1);
        ss += __shfl_xor(ss, 2);
        ss += __shfl_xor(ss, 4);
        ss += __shfl_xor(ss, 8);
        float inv = rsqrtf(ss * (1.0f / 64.0f) + 1e-5f);
        int row = g * 4 + r;
        int rowc = row < NT ? row : NT - 1;   // clamp LDS read
        int nr = m0 + row;
        if (row < NT && nr < n) {
#pragma unroll
            for (int tt = 0; tt < 4; ++tt) {
                int j = tt * 16 + c;
                float hl = (v[tt][r] - mu) * inv * gcol[tt] + btc[tt];
                float hv = b2f(hbs[wid][rowc][j]);
                float o = hv + fmaxf(hl, 0.0f);
                if (LAST) {
                    outF[(size_t)nr * HID + j] = o;
                } else {
                    hbout[(size_t)nr * HID + j] = f2b(o);
                    h8out[(size_t)nr * HID + j] = f2fp8(o);
                }
            }
        }
    }
}

// ---------------- launcher ----------------

extern "C" void kernel_launch(void* const* d_in, const int* in_sizes, int n_in,
                              void* d_out, int out_size, void* d_ws, size_t ws_size,
                              hipStream_t stream) {
    const float* x = (const float*)d_in[0];
    const int* edge_src = (const int*)d_in[1];
    const int* edge_dst = (const int*)d_in[2];
    const float* W_in = (const float*)d_in[3];
    const float* b_in = (const float*)d_in[4];
    const float* Ws_self = (const float*)d_in[5];
    const float* Ws_neigh = (const float*)d_in[6];
    const float* biases = (const float*)d_in[7];
    const float* gammas = (const float*)d_in[8];
    const float* betas = (const float*)d_in[9];
    float* out = (float*)d_out;

    int n = in_sizes[0] / 8;
    int e = in_sizes[1];
    int nb = (n + NPB - 1) >> BSHIFT;

    char* w = (char*)d_ws;
    size_t off = 0;
    auto carve = [&](size_t bytes) -> void* {
        void* p = w + off;
        off = (off + bytes + 255) & ~(size_t)255;
        return p;
    };
    int* offsets = (int*)carve((size_t)(n + 1) * 4);
    float* invdeg = (float*)carve((size_t)n * 4);
    int* bcnt = (int*)carve(1024 * 4);
    int* bbase = (int*)carve(1024 * 4);
    int* bcur = (int*)carve(1024 * 4);
    int* col = (int*)carve((size_t)e * 4);
    int* pairbuf = (int*)carve((size_t)e * 4);
    ushort* hb = (ushort*)carve((size_t)n * HID * 2);
    uchar* h8A = (uchar*)carve((size_t)n * HID);
    uchar* h8B = (uchar*)carve((size_t)n * HID);
    ushort* Wcat = (ushort*)carve(3 * 64 * 128 * 2);
    (void)ws_size;

    hipMemsetAsync(bcnt, 0, 1024 * 4, stream);
    hist_input<<<HISTB + 2048 + PREPB, 256, 0, stream>>>(edge_dst, bcnt, e, nb,
                                                         x, W_in, b_in, hb, h8A, n,
                                                         2048, Ws_self, Ws_neigh, Wcat);
    bucket_scan<<<1, 256, 0, stream>>>(bcnt, bbase, bcur, offsets, e, nb, n);
    partition<<<(e + P3TILE - 1) / P3TILE, 256, 0, stream>>>(edge_src, edge_dst, bcur,
                                                            pairbuf, e, nb);
    build_csr<<<nb, 1024, 0, stream>>>(pairbuf, bbase, offsets, invdeg, col, n);

    int ntiles = (n + NT - 1) / NT;
    int ablocks = (ntiles + 3) / 4;    // one NT-node tile per wave
    uchar* hin = h8A;
    uchar* hout = h8B;
    for (int l = 0; l < 3; ++l) {
        if (l < 2) {
            agg_tf<0><<<ablocks, 256, 0, stream>>>(hin, hb, hb, hout, out,
                                                   offsets, col, invdeg,
                                                   Wcat + (size_t)l * 8192,
                                                   biases + l * 64, gammas + l * 64,
                                                   betas + l * 64, n);
        } else {
            agg_tf<1><<<ablocks, 256, 0, stream>>>(hin, hb, hb, hout, out,
                                                   offsets, col, invdeg,
                                                   Wcat + (size_t)l * 8192,
                                                   biases + l * 64, gammas + l * 64,
                                                   betas + l * 64, n);
        }
        uchar* tmp = hin; hin = hout; hout = tmp;
    }
}

// Round 10
// 280.979 us; speedup vs baseline: 1.0725x; 1.0725x over previous
//
#include <hip/hip_runtime.h>

#define HID 64
#define BSHIFT 9            // 512 nodes per bucket
#define NPB 512
#define P3TILE 4096         // edges per block-tile in partition
#define HISTB 512           // hist blocks in fused hist+input kernel
#define PREPB 96            // prep_w blocks fused into hist_input
#define CSRK 20             // cached pair entries per thread in build_csr

typedef unsigned int uint;
typedef unsigned short ushort;
typedef unsigned char uchar;
typedef float f32x2 __attribute__((ext_vector_type(2)));
typedef float f32x4 __attribute__((ext_vector_type(4)));
typedef short bf16x8 __attribute__((ext_vector_type(8)));

__device__ inline ushort f2b(float f) {  // fp32 -> bf16 RNE
    uint u = __float_as_uint(f);
    return (ushort)((u + 0x7fffu + ((u >> 16) & 1u)) >> 16);
}

__device__ inline float b2f(ushort b) { return __uint_as_float((uint)b << 16); }

// unpack 16 fp8-e4m3 (uint4) and accumulate into a[8] float2 pairs.
__device__ inline void accf8(f32x2* a, uint4 hv) {
    a[0] += __builtin_bit_cast(f32x2, __builtin_amdgcn_cvt_pk_f32_fp8(hv.x, false));
    a[1] += __builtin_bit_cast(f32x2, __builtin_amdgcn_cvt_pk_f32_fp8(hv.x, true));
    a[2] += __builtin_bit_cast(f32x2, __builtin_amdgcn_cvt_pk_f32_fp8(hv.y, false));
    a[3] += __builtin_bit_cast(f32x2, __builtin_amdgcn_cvt_pk_f32_fp8(hv.y, true));
    a[4] += __builtin_bit_cast(f32x2, __builtin_amdgcn_cvt_pk_f32_fp8(hv.z, false));
    a[5] += __builtin_bit_cast(f32x2, __builtin_amdgcn_cvt_pk_f32_fp8(hv.z, true));
    a[6] += __builtin_bit_cast(f32x2, __builtin_amdgcn_cvt_pk_f32_fp8(hv.w, false));
    a[7] += __builtin_bit_cast(f32x2, __builtin_amdgcn_cvt_pk_f32_fp8(hv.w, true));
}

__device__ inline uchar f2fp8(float f) {
    return (uchar)(__builtin_amdgcn_cvt_pk_fp8_f32(f, f, 0, false) & 0xff);
}

// ------- fused: bucket histogram + input transform + weight prep -------

__global__ __launch_bounds__(256) void hist_input(const int* __restrict__ dst,
                                                  int* __restrict__ bcnt, int e, int nb,
                                                  const float* __restrict__ x,
                                                  const float* __restrict__ W_in,
                                                  const float* __restrict__ b_in,
                                                  ushort* __restrict__ hb,
                                                  uchar* __restrict__ h8, int n,
                                                  int inb,
                                                  const float* __restrict__ Ws,
                                                  const float* __restrict__ Wn,
                                                  ushort* __restrict__ Wcat) {
    __shared__ float smem[576];
    int t = threadIdx.x;
    int b = blockIdx.x;
    if (b < HISTB) {
        int* lh = (int*)smem;
        lh[t] = 0;
        __syncthreads();
        int e4c = e >> 2;                 // int4 count
        const int4* d4 = (const int4*)dst;
        for (int i = b * 256 + t; i < e4c; i += HISTB * 256) {
            int4 dv = d4[i];
            atomicAdd(&lh[dv.x >> BSHIFT], 1);
            atomicAdd(&lh[dv.y >> BSHIFT], 1);
            atomicAdd(&lh[dv.z >> BSHIFT], 1);
            atomicAdd(&lh[dv.w >> BSHIFT], 1);
        }
        if (b == 0) {                      // scalar tail (<4 edges)
            for (int i = e4c * 4 + t; i < e; i += 256)
                atomicAdd(&lh[dst[i] >> BSHIFT], 1);
        }
        __syncthreads();
        if (t < nb && lh[t]) atomicAdd(&bcnt[t], lh[t]);
        return;
    }
    if (b >= HISTB + inb) {   // weight prep range
        int i = (b - HISTB - inb) * 256 + t;
        if (i < 3 * 8192) {
            int l = i >> 13;
            int r = i & 8191;
            int j = r >> 7;
            int k = r & 127;
            float v = (k < 64) ? Ws[l * 4096 + j * 64 + k]
                               : Wn[l * 4096 + j * 64 + (k - 64)];
            Wcat[i] = f2b(v);
        }
        return;
    }
    int ib = b - HISTB;
    float* WlT = smem;          // [8][64]
    float* bl = smem + 512;     // [64]
    for (int i = t; i < 512; i += 256) {
        int j = i >> 3, k = i & 7;
        WlT[k * 64 + j] = W_in[i];
    }
    if (t < 64) bl[t] = b_in[t];
    __syncthreads();
    int total2 = n * 32;
    for (int i = ib * 256 + t; i < total2; i += inb * 256) {
        int v = i >> 5;
        int jp = i & 31;
        int j0 = jp * 2, j1 = jp * 2 + 1;
        const float* xr = x + (size_t)v * 8;
        float s0 = bl[j0], s1 = bl[j1];
#pragma unroll
        for (int k = 0; k < 8; ++k) {
            float xv = xr[k];
            s0 += xv * WlT[k * 64 + j0];
            s1 += xv * WlT[k * 64 + j1];
        }
        float o0 = fmaxf(s0, 0.0f), o1 = fmaxf(s1, 0.0f);
        ((uint*)hb)[i] = (uint)f2b(o0) | ((uint)f2b(o1) << 16);
        int pk = __builtin_amdgcn_cvt_pk_fp8_f32(o0, o1, 0, false);
        *(ushort*)&h8[(size_t)2 * i] = (ushort)(pk & 0xffff);
    }
}

__global__ void bucket_scan(const int* __restrict__ bcnt, int* __restrict__ bbase,
                            int* __restrict__ bcur, int* __restrict__ offsets,
                            int e, int nb, int n) {
    __shared__ int sd[256];
    int t = threadIdx.x;
    int v = (t < nb) ? bcnt[t] : 0;
    sd[t] = v;
    __syncthreads();
    for (int off = 1; off < 256; off <<= 1) {
        int u = (t >= off) ? sd[t - off] : 0;
        __syncthreads();
        sd[t] += u;
        __syncthreads();
    }
    int excl = t ? sd[t - 1] : 0;
    if (t < nb) { bbase[t] = excl; bcur[t] = excl; }
    if (t == nb) bbase[t] = e;
    if (t == 0) offsets[n] = e;
}

// partition edges into bucket-contiguous packed (src<<9 | dst&511) array.
__global__ __launch_bounds__(256) void partition(const int* __restrict__ src,
                                                 const int* __restrict__ dst,
                                                 int* __restrict__ bcur,
                                                 int* __restrict__ pair, int e, int nb) {
    __shared__ int lh[256], cb[256];
    int t = threadIdx.x;
    int base = blockIdx.x * P3TILE;
    lh[t] = 0;
    __syncthreads();
    int s[16], d[16], r[16];
    if (base + P3TILE <= e) {
        const int4* s4 = (const int4*)(src + base);
        const int4* d4 = (const int4*)(dst + base);
#pragma unroll
        for (int k = 0; k < 4; ++k) {
            int4 sv = s4[t * 4 + k];
            int4 dv = d4[t * 4 + k];
            s[k * 4 + 0] = sv.x; s[k * 4 + 1] = sv.y;
            s[k * 4 + 2] = sv.z; s[k * 4 + 3] = sv.w;
            d[k * 4 + 0] = dv.x; d[k * 4 + 1] = dv.y;
            d[k * 4 + 2] = dv.z; d[k * 4 + 3] = dv.w;
        }
#pragma unroll
        for (int k = 0; k < 16; ++k)
            r[k] = atomicAdd(&lh[d[k] >> BSHIFT], 1);
        __syncthreads();
        if (t < nb && lh[t]) cb[t] = atomicAdd(&bcur[t], lh[t]);
        __syncthreads();
#pragma unroll
        for (int k = 0; k < 16; ++k)
            pair[cb[d[k] >> BSHIFT] + r[k]] = (s[k] << BSHIFT) | (d[k] & (NPB - 1));
    } else {
#pragma unroll
        for (int k = 0; k < 16; ++k) {
            int i = base + t * 16 + k;
            if (i < e) {
                s[k] = src[i];
                d[k] = dst[i];
                r[k] = atomicAdd(&lh[d[k] >> BSHIFT], 1);
            }
        }
        __syncthreads();
        if (t < nb && lh[t]) cb[t] = atomicAdd(&bcur[t], lh[t]);
        __syncthreads();
#pragma unroll
        for (int k = 0; k < 16; ++k) {
            int i = base + t * 16 + k;
            if (i < e)
                pair[cb[d[k] >> BSHIFT] + r[k]] = (s[k] << BSHIFT) | (d[k] & (NPB - 1));
        }
    }
}

// 1024 threads/block: 16 waves for latency hiding.
// pair values are register-cached across the two passes (CSRK statically
// indexed regs + guarded fallback) -> one 12.8MB read instead of two.
__global__ __launch_bounds__(1024) void build_csr(const int* __restrict__ pair,
                                                  const int* __restrict__ bbase,
                                                  int* __restrict__ offsets,
                                                  float* __restrict__ invdeg,
                                                  int* __restrict__ col, int n) {
    __shared__ int bins[NPB], cur[NPB], sd[NPB];
    int b = blockIdx.x, t = threadIdx.x;
    int cbase = bbase[b], cend = bbase[b + 1];
    int v0 = b << BSHIFT;
    if (t < NPB) bins[t] = 0;
    __syncthreads();
    int rv[CSRK];
#pragma unroll
    for (int k = 0; k < CSRK; ++k) {
        int i = cbase + k * 1024 + t;
        if (i < cend) {
            rv[k] = pair[i];
            atomicAdd(&bins[rv[k] & (NPB - 1)], 1);
        }
    }
    for (int i = cbase + CSRK * 1024 + t; i < cend; i += 1024)   // overflow
        atomicAdd(&bins[pair[i] & (NPB - 1)], 1);
    __syncthreads();
    int d = (t < NPB) ? bins[t] : 0;
    if (t < NPB) sd[t] = d;
    __syncthreads();
    for (int off = 1; off < NPB; off <<= 1) {
        int u = (t < NPB && t >= off) ? sd[t - off] : 0;
        __syncthreads();
        if (t < NPB) sd[t] += u;
        __syncthreads();
    }
    if (t < NPB) {
        int excl = sd[t] - d;
        cur[t] = excl;
        int v = v0 + t;
        if (v < n) {
            offsets[v] = cbase + excl;
            invdeg[v] = d > 0 ? 1.0f / (float)d : 0.0f;
        }
    }
    __syncthreads();
#pragma unroll
    for (int k = 0; k < CSRK; ++k) {
        int i = cbase + k * 1024 + t;
        if (i < cend) {
            int p = rv[k];
            int pos = atomicAdd(&cur[p & (NPB - 1)], 1);
            col[cbase + pos] = p >> BSHIFT;
        }
    }
    for (int i = cbase + CSRK * 1024 + t; i < cend; i += 1024) { // overflow
        int p = pair[i];
        int pos = atomicAdd(&cur[p & (NPB - 1)], 1);
        col[cbase + pos] = p >> BSHIFT;
    }
}

// -------- fused aggregate + transform: one wave owns a 16-node tile --------
// Round-8 structure (best known, 66.5us/layer): hb tile staged once in
// wave-private LDS (coalesced uint4), serving MFMA A-frags and all residual
// reads. No barriers (slabs wave-private). h8 double-buffered across layers.

template <int LAST>
__global__ __launch_bounds__(256) void agg_tf(
    const uchar* __restrict__ h8in, const ushort* __restrict__ hbm,
    ushort* __restrict__ hbout, uchar* __restrict__ h8out,
    float* __restrict__ outF,
    const int* __restrict__ offsets, const int* __restrict__ col,
    const float* __restrict__ invdeg,
    const ushort* __restrict__ Wcat, const float* __restrict__ bias,
    const float* __restrict__ gamma, const float* __restrict__ beta, int n) {
    __shared__ ushort nmlds[4][16][72];   // neighbor means, pad 72
    __shared__ ushort hbs[4][16][76];     // staged hb tile, pad 76
    int t = threadIdx.x, lane = t & 63, wid = t >> 6;
    int ntiles = (n + 15) >> 4;
    int tile = blockIdx.x * 4 + wid;
    if (tile >= ntiles) return;
    int m0 = tile << 4;
    // ---- stage this wave's hb tile (16 rows x 64 cols bf16 = 2KB) ----
    {
        int row = lane >> 2;
        int ch = lane & 3;
        int node = m0 + row;
        int nl = node < n ? node : n - 1;
        const ushort* srcp = hbm + (size_t)nl * HID;
        *(uint4*)&hbs[wid][row][ch * 8] = *(const uint4*)&srcp[ch * 8];
        *(uint4*)&hbs[wid][row][32 + ch * 8] = *(const uint4*)&srcp[32 + ch * 8];
    }
    int q = lane >> 4;          // quarter -> node within pass
    int fl = lane & 15;         // col staging lane
    int e4 = lane & 3;          // which 16B of the 64B row
    int sl = (lane >> 2) & 3;   // edge slot
    // ---- aggregate 16 nodes in 4 passes of 4 ----
    for (int p = 0; p < 4; ++p) {
        int v = m0 + p * 4 + q;
        int vv = v < n ? v : n - 1;
        int o0 = offsets[vv], o1 = offsets[vv + 1];
        int deg = o1 - o0;
        const int* cp = col + o0;
        int deg16 = deg & ~15;
        f32x2 acc2[8];
        float* af = (float*)acc2;
#pragma unroll
        for (int k = 0; k < 8; ++k) acc2[k] = f32x2{0.f, 0.f};
        for (int base = 0; base < deg16; base += 16) {
            int idx16 = cp[base + fl];
#pragma unroll
            for (int jj = 0; jj < 16; jj += 4) {
                int ne = __shfl(idx16, q * 16 + jj + sl);
                uint4 hv = *(const uint4*)&h8in[(size_t)ne * HID + e4 * 16];
                accf8(acc2, hv);
            }
        }
        for (int jj = 0; jj < 16; jj += 4) {
            if (deg16 + jj >= deg) break;   // uniform within quarter
            int j = deg16 + jj + sl;
            if (j < deg) {
                int ne = cp[j];
                uint4 hv = *(const uint4*)&h8in[(size_t)ne * HID + e4 * 16];
                accf8(acc2, hv);
            }
        }
#pragma unroll
        for (int k = 0; k < 16; ++k) {
            af[k] += __shfl_xor(af[k], 4);
            af[k] += __shfl_xor(af[k], 8);
        }
        if (sl == 0) {
            float s = invdeg[vv];
            uint4 lo, hi;
            lo.x = (uint)f2b(af[0] * s) | ((uint)f2b(af[1] * s) << 16);
            lo.y = (uint)f2b(af[2] * s) | ((uint)f2b(af[3] * s) << 16);
            lo.z = (uint)f2b(af[4] * s) | ((uint)f2b(af[5] * s) << 16);
            lo.w = (uint)f2b(af[6] * s) | ((uint)f2b(af[7] * s) << 16);
            hi.x = (uint)f2b(af[8] * s) | ((uint)f2b(af[9] * s) << 16);
            hi.y = (uint)f2b(af[10] * s) | ((uint)f2b(af[11] * s) << 16);
            hi.z = (uint)f2b(af[12] * s) | ((uint)f2b(af[13] * s) << 16);
            hi.w = (uint)f2b(af[14] * s) | ((uint)f2b(af[15] * s) << 16);
            int row = p * 4 + q;
            *(uint4*)&nmlds[wid][row][e4 * 16] = lo;
            *(uint4*)&nmlds[wid][row][e4 * 16 + 8] = hi;
        }
    }
    // LDS slabs are wave-private: no barrier needed (lgkmcnt ordering only).
    // ---- transform (round-3 math; A-frags + residual from LDS) ----
    int c = lane & 15, g = lane >> 4;
    bf16x8 Bf[4][4];
#pragma unroll
    for (int tt = 0; tt < 4; ++tt)
#pragma unroll
        for (int s = 0; s < 4; ++s)
            Bf[s][tt] = *(const bf16x8*)&Wcat[(tt * 16 + c) * 128 + s * 32 + g * 8];
    float bcol[4], gcol[4], btc[4];
#pragma unroll
    for (int tt = 0; tt < 4; ++tt) {
        bcol[tt] = bias[tt * 16 + c];
        gcol[tt] = gamma[tt * 16 + c];
        btc[tt] = beta[tt * 16 + c];
    }
    bf16x8 Af[4];
#pragma unroll
    for (int s = 0; s < 2; ++s)
        Af[s] = *(const bf16x8*)&hbs[wid][c][s * 32 + g * 8];
#pragma unroll
    for (int s = 0; s < 2; ++s)
        Af[2 + s] = *(const bf16x8*)&nmlds[wid][c][s * 32 + g * 8];
    f32x4 acc[4] = {{0, 0, 0, 0}, {0, 0, 0, 0}, {0, 0, 0, 0}, {0, 0, 0, 0}};
#pragma unroll
    for (int tt = 0; tt < 4; ++tt)
#pragma unroll
        for (int s = 0; s < 4; ++s)
            acc[tt] = __builtin_amdgcn_mfma_f32_16x16x32_bf16(Af[s], Bf[s][tt],
                                                             acc[tt], 0, 0, 0);
    float v[4][4];
#pragma unroll
    for (int tt = 0; tt < 4; ++tt)
#pragma unroll
        for (int r = 0; r < 4; ++r) v[tt][r] = acc[tt][r] + bcol[tt];
#pragma unroll
    for (int r = 0; r < 4; ++r) {
        float s = v[0][r] + v[1][r] + v[2][r] + v[3][r];
        s += __shfl_xor(s, 1);
        s += __shfl_xor(s, 2);
        s += __shfl_xor(s, 4);
        s += __shfl_xor(s, 8);
        float mu = s * (1.0f / 64.0f);
        float ss = 0.f;
#pragma unroll
        for (int tt = 0; tt < 4; ++tt) {
            float d = v[tt][r] - mu;
            ss += d * d;
        }
        ss += __shfl_xor(ss, 1);
        ss += __shfl_xor(ss, 2);
        ss += __shfl_xor(ss, 4);
        ss += __shfl_xor(ss, 8);
        float inv = rsqrtf(ss * (1.0f / 64.0f) + 1e-5f);
        int nr = m0 + g * 4 + r;
        if (nr < n) {
#pragma unroll
            for (int tt = 0; tt < 4; ++tt) {
                int j = tt * 16 + c;
                float hl = (v[tt][r] - mu) * inv * gcol[tt] + btc[tt];
                float hv = b2f(hbs[wid][g * 4 + r][j]);
                float o = hv + fmaxf(hl, 0.0f);
                if (LAST) {
                    outF[(size_t)nr * HID + j] = o;
                } else {
                    hbout[(size_t)nr * HID + j] = f2b(o);
                    h8out[(size_t)nr * HID + j] = f2fp8(o);
                }
            }
        }
    }
}

// ---------------- launcher ----------------

extern "C" void kernel_launch(void* const* d_in, const int* in_sizes, int n_in,
                              void* d_out, int out_size, void* d_ws, size_t ws_size,
                              hipStream_t stream) {
    const float* x = (const float*)d_in[0];
    const int* edge_src = (const int*)d_in[1];
    const int* edge_dst = (const int*)d_in[2];
    const float* W_in = (const float*)d_in[3];
    const float* b_in = (const float*)d_in[4];
    const float* Ws_self = (const float*)d_in[5];
    const float* Ws_neigh = (const float*)d_in[6];
    const float* biases = (const float*)d_in[7];
    const float* gammas = (const float*)d_in[8];
    const float* betas = (const float*)d_in[9];
    float* out = (float*)d_out;

    int n = in_sizes[0] / 8;
    int e = in_sizes[1];
    int nb = (n + NPB - 1) >> BSHIFT;

    char* w = (char*)d_ws;
    size_t off = 0;
    auto carve = [&](size_t bytes) -> void* {
        void* p = w + off;
        off = (off + bytes + 255) & ~(size_t)255;
        return p;
    };
    int* offsets = (int*)carve((size_t)(n + 1) * 4);
    float* invdeg = (float*)carve((size_t)n * 4);
    int* bcnt = (int*)carve(1024 * 4);
    int* bbase = (int*)carve(1024 * 4);
    int* bcur = (int*)carve(1024 * 4);
    int* col = (int*)carve((size_t)e * 4);
    int* pairbuf = (int*)carve((size_t)e * 4);
    ushort* hb = (ushort*)carve((size_t)n * HID * 2);
    uchar* h8A = (uchar*)carve((size_t)n * HID);
    uchar* h8B = (uchar*)carve((size_t)n * HID);
    ushort* Wcat = (ushort*)carve(3 * 64 * 128 * 2);
    (void)ws_size;

    hipMemsetAsync(bcnt, 0, 1024 * 4, stream);
    hist_input<<<HISTB + 2048 + PREPB, 256, 0, stream>>>(edge_dst, bcnt, e, nb,
                                                         x, W_in, b_in, hb, h8A, n,
                                                         2048, Ws_self, Ws_neigh, Wcat);
    bucket_scan<<<1, 256, 0, stream>>>(bcnt, bbase, bcur, offsets, e, nb, n);
    partition<<<(e + P3TILE - 1) / P3TILE, 256, 0, stream>>>(edge_src, edge_dst, bcur,
                                                            pairbuf, e, nb);
    build_csr<<<nb, 1024, 0, stream>>>(pairbuf, bbase, offsets, invdeg, col, n);

    int ntiles = (n + 15) >> 4;
    int ablocks = (ntiles + 3) / 4;    // one 16-node tile per wave
    uchar* hin = h8A;
    uchar* hout = h8B;
    for (int l = 0; l < 3; ++l) {
        if (l < 2) {
            agg_tf<0><<<ablocks, 256, 0, stream>>>(hin, hb, hb, hout, out,
                                                   offsets, col, invdeg,
                                                   Wcat + (size_t)l * 8192,
                                                   biases + l * 64, gammas + l * 64,
                                                   betas + l * 64, n);
        } else {
            agg_tf<1><<<ablocks, 256, 0, stream>>>(hin, hb, hb, hout, out,
                                                   offsets, col, invdeg,
                                                   Wcat + (size_t)l * 8192,
                                                   biases + l * 64, gammas + l * 64,
                                                   betas + l * 64, n);
        }
        uchar* tmp = hin; hin = hout; hout = tmp;
    }
}